// Round 4
// baseline (443.767 us; speedup 1.0000x reference)
//
#include <hip/hip_runtime.h>
#include <stdint.h>

#define EPS_F 1e-7f

typedef float f32x4 __attribute__((ext_vector_type(4)));
typedef short short8 __attribute__((ext_vector_type(8)));
typedef unsigned short u16;
typedef unsigned short ushort4v __attribute__((ext_vector_type(4)));
typedef unsigned int uint4v __attribute__((ext_vector_type(4)));

__device__ __forceinline__ short f2bf(float f) {
  unsigned u = __float_as_uint(f);
  unsigned r = u + 0x7FFFu + ((u >> 16) & 1u);
  return (short)(r >> 16);
}
__device__ __forceinline__ float bf2f(u16 u) {
  return __uint_as_float((unsigned)u << 16);
}

// ---------------------------------------------------------------------------
// Encoder tables:  f(x) = relu(x*w1 + b1) @ W2 + b2  (scalar x -> R^256)
// 129 segments with knots at -b1_j/w1_j.
// ---------------------------------------------------------------------------
__global__ void build_meta_kernel(const float* __restrict__ w1, const float* __restrict__ b1,
                                  float* __restrict__ knots, int* __restrict__ jrank,
                                  int* __restrict__ act0) {
  __shared__ float s_kx[128];
  int t = threadIdx.x;  // 0..127
  float w = w1[t], b = b1[t];
  float kx = (w != 0.0f) ? (-b / w) : 3.4e38f;
  s_kx[t] = kx;
  int a0 = (w < 0.0f) || (w == 0.0f && b > 0.0f);  // active at x = -inf
  __syncthreads();
  int r = 0;
  for (int i = 0; i < 128; ++i) {
    float o = s_kx[i];
    if (o < kx || (o == kx && i < t)) ++r;
  }
  jrank[t] = r;
  act0[t] = a0;
  knots[r] = kx;
}

// per-segment coefficients: grid = 129 blocks (seg), 256 threads (dim)
__global__ void build_seg_kernel(const float* __restrict__ w1, const float* __restrict__ b1,
                                 const float* __restrict__ w2, const float* __restrict__ b2,
                                 const int* __restrict__ jrank, const int* __restrict__ act0,
                                 float* __restrict__ segA, float* __restrict__ segB,
                                 unsigned* __restrict__ ABpack) {
  int s = blockIdx.x;   // 0..128
  int t = threadIdx.x;  // 0..255
  __shared__ float s_w1[128], s_b1[128];
  __shared__ int s_on[128];
  if (t < 128) {
    s_w1[t] = w1[t];
    s_b1[t] = b1[t];
    s_on[t] = act0[t] ^ (jrank[t] < s ? 1 : 0);
  }
  __syncthreads();
  float A = 0.0f, B = b2[t];
#pragma unroll 4
  for (int j = 0; j < 128; ++j) {
    if (s_on[j]) {
      float w2v = w2[j * 256 + t];
      A = fmaf(s_w1[j], w2v, A);
      B = fmaf(s_b1[j], w2v, B);
    }
  }
  segA[s * 256 + t] = A;
  segB[s * 256 + t] = B;
  if (ABpack) {
    unsigned a = (unsigned)(u16)f2bf(A);
    unsigned bb = (unsigned)(u16)f2bf(B);
    ABpack[s * 256 + t] = a | (bb << 16);
  }
}

// node encoder applied to x -> bf16 [n,256]
__global__ void apply_enc_kernel(const float* __restrict__ in, int nrows,
                                 const float* __restrict__ knots, const float* __restrict__ segA,
                                 const float* __restrict__ segB, u16* __restrict__ outbf) {
  __shared__ float s_kx[128];
  int t = threadIdx.x;
  if (t < 128) s_kx[t] = knots[t];
  __syncthreads();
  int r0 = blockIdx.x * 16;
  int rEnd = r0 + 16;
  if (rEnd > nrows) rEnd = nrows;
  for (int r = r0; r < rEnd; ++r) {
    float x = in[r];
    int lo = 0, hi = 128;
    while (lo < hi) { int mid = (lo + hi) >> 1; if (s_kx[mid] < x) lo = mid + 1; else hi = mid; }
    outbf[(size_t)r * 256 + t] = (u16)f2bf(fmaf(segA[lo * 256 + t], x, segB[lo * 256 + t]));
  }
}

__global__ void zero_kernel(int* __restrict__ p, int n) {
  int i = blockIdx.x * blockDim.x + threadIdx.x;
  if (i < n) p[i] = 0;
}

__global__ void hist_kernel(const int* __restrict__ dst, int E, int* __restrict__ counts) {
  int i = blockIdx.x * blockDim.x + threadIdx.x;
  if (i < E) atomicAdd(&counts[dst[i]], 1);
}

// 3-phase exclusive scan of counts[0..n) -> row_start[0..n], row_start[n]=E
__global__ void scan_p1_kernel(const int* __restrict__ counts, int n,
                               int* __restrict__ blocksums) {
  __shared__ int tmp[256];
  int t = threadIdx.x;
  int i = blockIdx.x * 256 + t;
  tmp[t] = (i < n) ? counts[i] : 0;
  __syncthreads();
  for (int off = 128; off > 0; off >>= 1) {
    if (t < off) tmp[t] += tmp[t + off];
    __syncthreads();
  }
  if (t == 0) blocksums[blockIdx.x] = tmp[0];
}

__global__ void scan_p2_kernel(int* __restrict__ blocksums, int nb) {
  __shared__ int tmp[256];
  int t = threadIdx.x;
  int v = (t < nb) ? blocksums[t] : 0;
  tmp[t] = v;
  __syncthreads();
  for (int off = 1; off < 256; off <<= 1) {
    int add = (t >= off) ? tmp[t - off] : 0;
    __syncthreads();
    tmp[t] += add;
    __syncthreads();
  }
  if (t < nb) blocksums[t] = tmp[t] - v;  // exclusive
}

__global__ void scan_p3_kernel(const int* __restrict__ counts, int n, int E,
                               const int* __restrict__ blocksums,
                               int* __restrict__ row_start) {
  __shared__ int tmp[256];
  int t = threadIdx.x;
  int i = blockIdx.x * 256 + t;
  int v = (i < n) ? counts[i] : 0;
  tmp[t] = v;
  __syncthreads();
  for (int off = 1; off < 256; off <<= 1) {
    int add = (t >= off) ? tmp[t - off] : 0;
    __syncthreads();
    tmp[t] += add;
    __syncthreads();
  }
  if (i < n) row_start[i] = blocksums[blockIdx.x] + tmp[t] - v;
  if (blockIdx.x == 0 && t == 0) row_start[n] = E;
}

// fill CSR: per edge, slot under its dst; entry packs {src | seg<<17, bits(x)}
__global__ void fill_kernel(const int* __restrict__ srcA, const int* __restrict__ dstA,
                            const float* __restrict__ eattr, int E,
                            const int* __restrict__ row_start, int* __restrict__ cursor,
                            const float* __restrict__ knotsE, int2* __restrict__ csr) {
  __shared__ float s_kx[128];
  if (threadIdx.x < 128) s_kx[threadIdx.x] = knotsE[threadIdx.x];
  __syncthreads();
  int i = blockIdx.x * blockDim.x + threadIdx.x;
  if (i >= E) return;
  int s = srcA[i], d = dstA[i];
  float x = eattr[i];
  int lo = 0, hi = 128;
  while (lo < hi) { int mid = (lo + hi) >> 1; if (s_kx[mid] < x) lo = mid + 1; else hi = mid; }
  int pos = row_start[d] + atomicAdd(&cursor[d], 1);
  csr[pos] = make_int2(s | (lo << 17), __float_as_int(x));
}

// convert gnn_w [4][K=256][N=256] f32 -> WT [4][N][K] bf16
__global__ void convw_kernel(const float* __restrict__ W, short* __restrict__ WT) {
  int l = blockIdx.x >> 8, nn = blockIdx.x & 255, k = threadIdx.x;
  WT[((size_t)l * 256 + nn) * 256 + k] = f2bf(W[((size_t)l * 256 + k) * 256 + nn]);
}

// ---------------------------------------------------------------------------
// Fused layer. Phase 1: 4-deep edge-batched aggregate (12 independent loads
// in flight per wave). Phase 2: 16x256 @ 256x256 MFMA from LDS A-tile.
// ---------------------------------------------------------------------------
__global__ __launch_bounds__(256) void layer_kernel(
    const u16* __restrict__ hbf, const int2* __restrict__ csr,
    const int* __restrict__ row_start, const unsigned* __restrict__ AB,
    const short* __restrict__ WT, const float* __restrict__ bias,
    float* __restrict__ houtf, u16* __restrict__ houtbf, int N) {
  __shared__ u16 As[16][264];
  int wv = threadIdx.x >> 6, lane = threadIdx.x & 63;
  int nbase = blockIdx.x * 16;
  int d0 = lane * 4;

  // ---- phase 1: aggregate 4 nodes per wave, 4 edges per iteration ----
  for (int i = 0; i < 4; ++i) {
    int r = wv * 4 + i;
    int v = nbase + r;
    f32x4 acc = {0.f, 0.f, 0.f, 0.f};
    if (v < N) {
      ushort4v sv = *(const ushort4v*)(hbf + (size_t)v * 256 + d0);
      acc.x = bf2f(sv.x); acc.y = bf2f(sv.y); acc.z = bf2f(sv.z); acc.w = bf2f(sv.w);
      int p0 = row_start[v], p1 = row_start[v + 1];
      for (int p = p0; p < p1; p += 4) {
        int q1 = (p + 1 < p1) ? p + 1 : p;
        int q2 = (p + 2 < p1) ? p + 2 : p;
        int q3 = (p + 3 < p1) ? p + 3 : p;
        // issue all independent loads back-to-back (4-deep MLP)
        int2 se0 = csr[p], se1 = csr[q1], se2 = csr[q2], se3 = csr[q3];
        int s0 = se0.x & 0x1FFFF, g0 = ((unsigned)se0.x) >> 17;
        int s1 = se1.x & 0x1FFFF, g1 = ((unsigned)se1.x) >> 17;
        int s2 = se2.x & 0x1FFFF, g2 = ((unsigned)se2.x) >> 17;
        int s3 = se3.x & 0x1FFFF, g3 = ((unsigned)se3.x) >> 17;
        ushort4v hv0 = *(const ushort4v*)(hbf + (size_t)s0 * 256 + d0);
        ushort4v hv1 = *(const ushort4v*)(hbf + (size_t)s1 * 256 + d0);
        ushort4v hv2 = *(const ushort4v*)(hbf + (size_t)s2 * 256 + d0);
        ushort4v hv3 = *(const ushort4v*)(hbf + (size_t)s3 * 256 + d0);
        uint4v ab0 = *(const uint4v*)(AB + (size_t)g0 * 256 + d0);
        uint4v ab1 = *(const uint4v*)(AB + (size_t)g1 * 256 + d0);
        uint4v ab2 = *(const uint4v*)(AB + (size_t)g2 * 256 + d0);
        uint4v ab3 = *(const uint4v*)(AB + (size_t)g3 * 256 + d0);
        float x0 = __int_as_float(se0.y);
        float x1 = __int_as_float(se1.y);
        float x2 = __int_as_float(se2.y);
        float x3 = __int_as_float(se3.y);
        float m1 = (p + 1 < p1) ? 1.0f : 0.0f;
        float m2 = (p + 2 < p1) ? 1.0f : 0.0f;
        float m3 = (p + 3 < p1) ? 1.0f : 0.0f;
#pragma unroll
        for (int j = 0; j < 4; ++j) {
          float t0 = bf2f((u16)(hv0[j])) + fmaf(__uint_as_float(ab0[j] << 16), x0,
                                                __uint_as_float(ab0[j] & 0xFFFF0000u));
          acc[j] += fmaxf(t0, 0.0f);
          float t1 = bf2f((u16)(hv1[j])) + fmaf(__uint_as_float(ab1[j] << 16), x1,
                                                __uint_as_float(ab1[j] & 0xFFFF0000u));
          acc[j] = fmaf(m1, fmaxf(t1, 0.0f), acc[j]);
          float t2 = bf2f((u16)(hv2[j])) + fmaf(__uint_as_float(ab2[j] << 16), x2,
                                                __uint_as_float(ab2[j] & 0xFFFF0000u));
          acc[j] = fmaf(m2, fmaxf(t2, 0.0f), acc[j]);
          float t3 = bf2f((u16)(hv3[j])) + fmaf(__uint_as_float(ab3[j] << 16), x3,
                                                __uint_as_float(ab3[j] & 0xFFFF0000u));
          acc[j] = fmaf(m3, fmaxf(t3, 0.0f), acc[j]);
        }
      }
      float de = (float)(p1 - p0) * EPS_F;
      acc.x += de; acc.y += de; acc.z += de; acc.w += de;
    }
    ushort4v ob;
    ob.x = (u16)f2bf(acc.x); ob.y = (u16)f2bf(acc.y);
    ob.z = (u16)f2bf(acc.z); ob.w = (u16)f2bf(acc.w);
    *(ushort4v*)&As[r][d0] = ob;
  }
  __syncthreads();

  // ---- phase 2: [16,256] @ [256,256] ----
  int colb = lane & 15, rowf = lane & 15, kgrp = (lane >> 4) * 8;
  int c0 = wv * 64;
  const short* wtc = WT + (size_t)(c0 + colb) * 256;
  const u16* Ar = &As[rowf][0];
  f32x4 acc0 = {0.f, 0.f, 0.f, 0.f}, acc1 = acc0, acc2 = acc0, acc3 = acc0;
  short8 b0 = *(const short8*)(wtc + kgrp);
  short8 b1 = *(const short8*)(wtc + 4096 + kgrp);
  short8 b2 = *(const short8*)(wtc + 8192 + kgrp);
  short8 b3 = *(const short8*)(wtc + 12288 + kgrp);
#pragma unroll
  for (int kt = 0; kt < 8; ++kt) {
    int k0 = kt * 32 + kgrp;
    short8 af = *(const short8*)(Ar + k0);
    short8 n0, n1, n2, n3;
    if (kt < 7) {
      int kn = k0 + 32;
      n0 = *(const short8*)(wtc + kn);
      n1 = *(const short8*)(wtc + 4096 + kn);
      n2 = *(const short8*)(wtc + 8192 + kn);
      n3 = *(const short8*)(wtc + 12288 + kn);
    }
    acc0 = __builtin_amdgcn_mfma_f32_16x16x32_bf16(af, b0, acc0, 0, 0, 0);
    acc1 = __builtin_amdgcn_mfma_f32_16x16x32_bf16(af, b1, acc1, 0, 0, 0);
    acc2 = __builtin_amdgcn_mfma_f32_16x16x32_bf16(af, b2, acc2, 0, 0, 0);
    acc3 = __builtin_amdgcn_mfma_f32_16x16x32_bf16(af, b3, acc3, 0, 0, 0);
    if (kt < 7) { b0 = n0; b1 = n1; b2 = n2; b3 = n3; }
  }
  int rbase = (lane >> 4) * 4;
#pragma unroll
  for (int nb = 0; nb < 4; ++nb) {
    f32x4 a = (nb == 0) ? acc0 : (nb == 1) ? acc1 : (nb == 2) ? acc2 : acc3;
    int col = c0 + nb * 16 + colb;
    float bv = bias[col];
#pragma unroll
    for (int rr = 0; rr < 4; ++rr) {
      int vv = nbase + rbase + rr;
      if (vv < N) {
        float val = a[rr] + bv;
        if (houtf) houtf[(size_t)vv * 256 + col] = val;
        if (houtbf) houtbf[(size_t)vv * 256 + col] = (u16)f2bf(val);
      }
    }
  }
}

// out = h @ out_w[256,3] + out_b ; one node per wave
__global__ void head_kernel(const float* __restrict__ h, const float* __restrict__ ow,
                            const float* __restrict__ ob, float* __restrict__ out, int n) {
  __shared__ float sw[768];
  for (int i = threadIdx.x; i < 768; i += 256) sw[i] = ow[i];
  __syncthreads();
  int wv = threadIdx.x >> 6, lane = threadIdx.x & 63;
  int v = blockIdx.x * 4 + wv;
  if (v >= n) return;
  f32x4 hv = *(const f32x4*)(h + (size_t)v * 256 + lane * 4);
  int d0 = lane * 4;
#pragma unroll
  for (int o = 0; o < 3; ++o) {
    float s = hv.x * sw[(d0 + 0) * 3 + o] + hv.y * sw[(d0 + 1) * 3 + o] +
              hv.z * sw[(d0 + 2) * 3 + o] + hv.w * sw[(d0 + 3) * 3 + o];
#pragma unroll
    for (int off = 32; off > 0; off >>= 1) s += __shfl_down(s, off);
    if (lane == 0) out[(size_t)v * 3 + o] = s + ob[o];
  }
}

// ---------------------------------------------------------------------------
extern "C" void kernel_launch(void* const* d_in, const int* in_sizes, int n_in,
                              void* d_out, int out_size, void* d_ws, size_t ws_size,
                              hipStream_t stream) {
  const float* x     = (const float*)d_in[0];
  const float* eattr = (const float*)d_in[1];
  const int*   eidx  = (const int*)d_in[2];
  const float* nw1 = (const float*)d_in[3];
  const float* nb1 = (const float*)d_in[4];
  const float* nw2 = (const float*)d_in[5];
  const float* nb2 = (const float*)d_in[6];
  const float* ew1 = (const float*)d_in[7];
  const float* eb1 = (const float*)d_in[8];
  const float* ew2 = (const float*)d_in[9];
  const float* eb2 = (const float*)d_in[10];
  const float* gw  = (const float*)d_in[11];
  const float* gb  = (const float*)d_in[12];
  const float* ow  = (const float*)d_in[13];
  const float* ob  = (const float*)d_in[14];

  int N = in_sizes[0];
  int E = in_sizes[1];
  const int* srcA = eidx;
  const int* dstA = eidx + E;

  char* ws = (char*)d_ws;
  auto al = [](size_t v) { return (v + 255) & ~(size_t)255; };
  size_t off = 0;
  float* hA    = (float*)(ws + off); off = al(off + (size_t)N * 256 * 4);   // final f32 h
  u16* hbfA    = (u16*)(ws + off);   off = al(off + (size_t)N * 256 * 2);
  u16* hbfB    = (u16*)(ws + off);   off = al(off + (size_t)N * 256 * 2);
  short* WT    = (short*)(ws + off); off = al(off + (size_t)4 * 256 * 256 * 2);
  float* knN   = (float*)(ws + off); off = al(off + 128 * 4);
  float* AN    = (float*)(ws + off); off = al(off + 129 * 256 * 4);
  float* BN    = (float*)(ws + off); off = al(off + 129 * 256 * 4);
  float* knE   = (float*)(ws + off); off = al(off + 128 * 4);
  float* AE    = (float*)(ws + off); off = al(off + 129 * 256 * 4);
  float* BE    = (float*)(ws + off); off = al(off + 129 * 256 * 4);
  unsigned* ABE = (unsigned*)(ws + off); off = al(off + 129 * 256 * 4);
  int* rankN   = (int*)(ws + off);   off = al(off + 128 * 4);
  int* act0N   = (int*)(ws + off);   off = al(off + 128 * 4);
  int* rankE   = (int*)(ws + off);   off = al(off + 128 * 4);
  int* act0E   = (int*)(ws + off);   off = al(off + 128 * 4);
  int* rowSt   = (int*)(ws + off);   off = al(off + (size_t)(N + 1) * 4);
  int* counts  = (int*)(ws + off);   off = al(off + (size_t)N * 4);
  int* bsums   = (int*)(ws + off);   off = al(off + 256 * 4);
  int2* csr    = (int2*)(ws + off);  off = al(off + (size_t)E * 8);
  (void)ws_size; (void)n_in; (void)out_size;

  // encoder tables (parallel build)
  build_meta_kernel<<<1, 128, 0, stream>>>(nw1, nb1, knN, rankN, act0N);
  build_meta_kernel<<<1, 128, 0, stream>>>(ew1, eb1, knE, rankE, act0E);
  build_seg_kernel<<<129, 256, 0, stream>>>(nw1, nb1, nw2, nb2, rankN, act0N, AN, BN, nullptr);
  build_seg_kernel<<<129, 256, 0, stream>>>(ew1, eb1, ew2, eb2, rankE, act0E, AE, BE, ABE);

  // node encoder -> hbfA
  apply_enc_kernel<<<(N + 15) / 16, 256, 0, stream>>>(x, N, knN, AN, BN, hbfA);

  // CSR build
  int gN = (N + 255) / 256, gE = (E + 255) / 256;
  zero_kernel<<<gN, 256, 0, stream>>>(counts, N);
  hist_kernel<<<gE, 256, 0, stream>>>(dstA, E, counts);
  scan_p1_kernel<<<gN, 256, 0, stream>>>(counts, N, bsums);
  scan_p2_kernel<<<1, 256, 0, stream>>>(bsums, gN);
  scan_p3_kernel<<<gN, 256, 0, stream>>>(counts, N, E, bsums, rowSt);
  zero_kernel<<<gN, 256, 0, stream>>>(counts, N);
  fill_kernel<<<gE, 256, 0, stream>>>(srcA, dstA, eattr, E, rowSt, counts, knE, csr);

  // weights -> bf16 transposed
  convw_kernel<<<4 * 256, 256, 0, stream>>>(gw, WT);

  // fused layers
  u16* hbc = hbfA;
  u16* hbn = hbfB;
  int gLayer = (N + 15) / 16;
  for (int l = 0; l < 4; ++l) {
    float* hf = (l == 3) ? hA : nullptr;      // f32 only needed by head
    u16* hbo = (l == 3) ? nullptr : hbn;
    layer_kernel<<<gLayer, 256, 0, stream>>>(hbc, csr, rowSt, ABE,
                                             WT + (size_t)l * 256 * 256,
                                             gb + (size_t)l * 256, hf, hbo, N);
    u16* t = hbc; hbc = hbn; hbn = t;
  }

  head_kernel<<<(N + 3) / 4, 256, 0, stream>>>(hA, ow, ob, (float*)d_out, N);
}

// Round 5
// 404.864 us; speedup vs baseline: 1.0961x; 1.0961x over previous
//
#include <hip/hip_runtime.h>
#include <stdint.h>

#define EPS_F 1e-7f

typedef float f32x4 __attribute__((ext_vector_type(4)));
typedef short short8 __attribute__((ext_vector_type(8)));
typedef unsigned short u16;
typedef unsigned short ushort4v __attribute__((ext_vector_type(4)));
typedef unsigned int uint4v __attribute__((ext_vector_type(4)));

__device__ __forceinline__ short f2bf(float f) {
  unsigned u = __float_as_uint(f);
  unsigned r = u + 0x7FFFu + ((u >> 16) & 1u);
  return (short)(r >> 16);
}
__device__ __forceinline__ float bf2f(u16 u) {
  return __uint_as_float((unsigned)u << 16);
}

// ---------------------------------------------------------------------------
// Encoder tables:  f(x) = relu(x*w1 + b1) @ W2 + b2  (scalar x -> R^256)
// 129 segments with knots at -b1_j/w1_j.  segsel (optional): the segment ids
// for x=-1 and x=+1 (register-cache hints for the aggregate kernel).
// ---------------------------------------------------------------------------
__global__ void build_meta_kernel(const float* __restrict__ w1, const float* __restrict__ b1,
                                  float* __restrict__ knots, int* __restrict__ jrank,
                                  int* __restrict__ act0, int* __restrict__ segsel) {
  __shared__ float s_kx[128];
  __shared__ float s_sorted[128];
  int t = threadIdx.x;  // 0..127
  float w = w1[t], b = b1[t];
  float kx = (w != 0.0f) ? (-b / w) : 3.4e38f;
  s_kx[t] = kx;
  int a0 = (w < 0.0f) || (w == 0.0f && b > 0.0f);  // active at x = -inf
  __syncthreads();
  int r = 0;
  for (int i = 0; i < 128; ++i) {
    float o = s_kx[i];
    if (o < kx || (o == kx && i < t)) ++r;
  }
  jrank[t] = r;
  act0[t] = a0;
  knots[r] = kx;
  s_sorted[r] = kx;
  __syncthreads();
  if (t == 0 && segsel) {
    int lo = 0, hi = 128;
    while (lo < hi) { int m = (lo + hi) >> 1; if (s_sorted[m] < -1.0f) lo = m + 1; else hi = m; }
    segsel[0] = lo;
    lo = 0; hi = 128;
    while (lo < hi) { int m = (lo + hi) >> 1; if (s_sorted[m] < 1.0f) lo = m + 1; else hi = m; }
    segsel[1] = lo;
  }
}

// per-segment coefficients: grid = 129 blocks (seg), 256 threads (dim)
__global__ void build_seg_kernel(const float* __restrict__ w1, const float* __restrict__ b1,
                                 const float* __restrict__ w2, const float* __restrict__ b2,
                                 const int* __restrict__ jrank, const int* __restrict__ act0,
                                 float* __restrict__ segA, float* __restrict__ segB,
                                 unsigned* __restrict__ ABpack) {
  int s = blockIdx.x;   // 0..128
  int t = threadIdx.x;  // 0..255
  __shared__ float s_w1[128], s_b1[128];
  __shared__ int s_on[128];
  if (t < 128) {
    s_w1[t] = w1[t];
    s_b1[t] = b1[t];
    s_on[t] = act0[t] ^ (jrank[t] < s ? 1 : 0);
  }
  __syncthreads();
  float A = 0.0f, B = b2[t];
#pragma unroll 4
  for (int j = 0; j < 128; ++j) {
    if (s_on[j]) {
      float w2v = w2[j * 256 + t];
      A = fmaf(s_w1[j], w2v, A);
      B = fmaf(s_b1[j], w2v, B);
    }
  }
  segA[s * 256 + t] = A;
  segB[s * 256 + t] = B;
  if (ABpack) {
    unsigned a = (unsigned)(u16)f2bf(A);
    unsigned bb = (unsigned)(u16)f2bf(B);
    ABpack[s * 256 + t] = a | (bb << 16);
  }
}

// node encoder applied to x -> bf16 [n,256]
__global__ void apply_enc_kernel(const float* __restrict__ in, int nrows,
                                 const float* __restrict__ knots, const float* __restrict__ segA,
                                 const float* __restrict__ segB, u16* __restrict__ outbf) {
  __shared__ float s_kx[128];
  int t = threadIdx.x;
  if (t < 128) s_kx[t] = knots[t];
  __syncthreads();
  int r0 = blockIdx.x * 16;
  int rEnd = r0 + 16;
  if (rEnd > nrows) rEnd = nrows;
  for (int r = r0; r < rEnd; ++r) {
    float x = in[r];
    int lo = 0, hi = 128;
    while (lo < hi) { int mid = (lo + hi) >> 1; if (s_kx[mid] < x) lo = mid + 1; else hi = mid; }
    outbf[(size_t)r * 256 + t] = (u16)f2bf(fmaf(segA[lo * 256 + t], x, segB[lo * 256 + t]));
  }
}

__global__ void zero_kernel(int* __restrict__ p, int n) {
  int i = blockIdx.x * blockDim.x + threadIdx.x;
  if (i < n) p[i] = 0;
}

// pre-fill (padded) CSR with pad entries: bit31 set, src=0, seg=0, x=0
__global__ void initcsr_kernel(int2* __restrict__ csr, int n) {
  int i = blockIdx.x * blockDim.x + threadIdx.x;
  if (i < n) csr[i] = make_int2((int)0x80000000, 0);
}

__global__ void hist_kernel(const int* __restrict__ dst, int E, int* __restrict__ counts) {
  int i = blockIdx.x * blockDim.x + threadIdx.x;
  if (i < E) atomicAdd(&counts[dst[i]], 1);
}

// 3-phase exclusive scan of PADDED counts  (deg rounded up to multiple of 4)
__global__ void scan_p1_kernel(const int* __restrict__ counts, int n,
                               int* __restrict__ blocksums) {
  __shared__ int tmp[256];
  int t = threadIdx.x;
  int i = blockIdx.x * 256 + t;
  int c = (i < n) ? counts[i] : 0;
  tmp[t] = (c + 3) & ~3;
  __syncthreads();
  for (int off = 128; off > 0; off >>= 1) {
    if (t < off) tmp[t] += tmp[t + off];
    __syncthreads();
  }
  if (t == 0) blocksums[blockIdx.x] = tmp[0];
}

__global__ void scan_p2_kernel(int* __restrict__ blocksums, int nb,
                               int* __restrict__ row_start, int n) {
  __shared__ int tmp[256];
  int t = threadIdx.x;
  int v = (t < nb) ? blocksums[t] : 0;
  tmp[t] = v;
  __syncthreads();
  for (int off = 1; off < 256; off <<= 1) {
    int add = (t >= off) ? tmp[t - off] : 0;
    __syncthreads();
    tmp[t] += add;
    __syncthreads();
  }
  if (t < nb) blocksums[t] = tmp[t] - v;  // exclusive
  if (t == 0) row_start[n] = tmp[255];    // padded total
}

__global__ void scan_p3_kernel(const int* __restrict__ counts, int n,
                               const int* __restrict__ blocksums,
                               int* __restrict__ row_start) {
  __shared__ int tmp[256];
  int t = threadIdx.x;
  int i = blockIdx.x * 256 + t;
  int c = (i < n) ? counts[i] : 0;
  int v = (c + 3) & ~3;
  tmp[t] = v;
  __syncthreads();
  for (int off = 1; off < 256; off <<= 1) {
    int add = (t >= off) ? tmp[t - off] : 0;
    __syncthreads();
    tmp[t] += add;
    __syncthreads();
  }
  if (i < n) row_start[i] = blocksums[blockIdx.x] + tmp[t] - v;
}

// fill CSR: per edge, slot under its dst; entry packs {src | seg<<17, bits(x)}
__global__ void fill_kernel(const int* __restrict__ srcA, const int* __restrict__ dstA,
                            const float* __restrict__ eattr, int E,
                            const int* __restrict__ row_start, int* __restrict__ cursor,
                            const float* __restrict__ knotsE, int2* __restrict__ csr) {
  __shared__ float s_kx[128];
  if (threadIdx.x < 128) s_kx[threadIdx.x] = knotsE[threadIdx.x];
  __syncthreads();
  int i = blockIdx.x * blockDim.x + threadIdx.x;
  if (i >= E) return;
  int s = srcA[i], d = dstA[i];
  float x = eattr[i];
  int lo = 0, hi = 128;
  while (lo < hi) { int mid = (lo + hi) >> 1; if (s_kx[mid] < x) lo = mid + 1; else hi = mid; }
  int pos = row_start[d] + atomicAdd(&cursor[d], 1);
  csr[pos] = make_int2(s | (lo << 17), __float_as_int(x));
}

// convert gnn_w [4][K=256][N=256] f32 -> WT [4][N][K] bf16
__global__ void convw_kernel(const float* __restrict__ W, short* __restrict__ WT) {
  int l = blockIdx.x >> 8, nn = blockIdx.x & 255, k = threadIdx.x;
  WT[((size_t)l * 256 + nn) * 256 + k] = f2bf(W[((size_t)l * 256 + k) * 256 + nn]);
}

// ---------------------------------------------------------------------------
// Fused layer.  Phase 1: wave owns 4 nodes = one contiguous quad-aligned CSR
// range; one coalesced csr load per 64 slots + __shfl fan-out; 2-quad
// software pipeline; AB rows register-cached (2 live segments).
// Phase 2: 16x256 @ 256x256 MFMA from LDS A-tile.
// ---------------------------------------------------------------------------
struct Quad {
  ushort4v hv[4];
  uint4v ab[4];
  f32x4 x;
  f32x4 m;
};

__global__ __launch_bounds__(256, 4) void layer_kernel(
    const u16* __restrict__ hbf, const int2* __restrict__ csr,
    const int* __restrict__ rowSt, const int* __restrict__ deg,
    const unsigned* __restrict__ AB, const int* __restrict__ segsel,
    const short* __restrict__ WT, const float* __restrict__ bias,
    float* __restrict__ houtf, u16* __restrict__ houtbf, int N) {
  __shared__ u16 As[16][264];
  int wv = threadIdx.x >> 6, lane = threadIdx.x & 63;
  int nbase = blockIdx.x * 16;
  int d0 = lane * 4;
  int v0 = nbase + wv * 4;

  int segN = segsel[0], segP = segsel[1];
  uint4v abN = *(const uint4v*)(AB + (size_t)segN * 256 + d0);
  uint4v abP = *(const uint4v*)(AB + (size_t)segP * 256 + d0);

  int P0 = rowSt[v0];
  int b1v = rowSt[v0 + 1], b2v = rowSt[v0 + 2], b3v = rowSt[v0 + 3];
  int P4 = rowSt[v0 + 4];

  // phase 0: pre-store self + deg*eps into the A-tile rows
#pragma unroll
  for (int i = 0; i < 4; ++i) {
    int v = v0 + i;
    ushort4v sv = *(const ushort4v*)(hbf + (size_t)v * 256 + d0);
    float de = (float)deg[v] * EPS_F;
    ushort4v ob;
    ob.x = (u16)f2bf(bf2f(sv.x) + de);
    ob.y = (u16)f2bf(bf2f(sv.y) + de);
    ob.z = (u16)f2bf(bf2f(sv.z) + de);
    ob.w = (u16)f2bf(bf2f(sv.w) + de);
    *(ushort4v*)&As[wv * 4 + i][d0] = ob;
  }

  f32x4 acc = {0.f, 0.f, 0.f, 0.f};
  int node = 0;
  int nb = b1v;

  auto fetchq = [&](int off, const int2& ms) {
    Quad q;
#pragma unroll
    for (int i = 0; i < 4; ++i) {
      int ex = __shfl(ms.x, off + i);
      int ey = __shfl(ms.y, off + i);
      int s = ex & 0x1FFFF;
      int g = (ex >> 17) & 0xFF;
      q.m[i] = (ex >= 0) ? 1.0f : 0.0f;
      q.x[i] = __int_as_float(ey);
      q.hv[i] = *(const ushort4v*)(hbf + (size_t)s * 256 + d0);
      uint4v ab = (g == segP) ? abP : abN;
      if (__builtin_expect(g != segP && g != segN, 0))
        ab = *(const uint4v*)(AB + (size_t)g * 256 + d0);
      q.ab[i] = ab;
    }
    return q;
  };
  auto computeq = [&](const Quad& q) {
#pragma unroll
    for (int i = 0; i < 4; ++i) {
#pragma unroll
      for (int j = 0; j < 4; ++j) {
        float Af = __uint_as_float(q.ab[i][j] << 16);
        float Bf = __uint_as_float(q.ab[i][j] & 0xFFFF0000u);
        float t = bf2f(q.hv[i][j]) + fmaf(Af, q.x[i], Bf);
        acc[j] = fmaf(q.m[i], fmaxf(t, 0.0f), acc[j]);
      }
    }
  };
  auto flushn = [&]() {
    int r = wv * 4 + node;
    ushort4v cur = *(ushort4v*)&As[r][d0];
    ushort4v ob;
    ob.x = (u16)f2bf(bf2f(cur.x) + acc.x);
    ob.y = (u16)f2bf(bf2f(cur.y) + acc.y);
    ob.z = (u16)f2bf(bf2f(cur.z) + acc.z);
    ob.w = (u16)f2bf(bf2f(cur.w) + acc.w);
    *(ushort4v*)&As[r][d0] = ob;
    acc.x = 0.f; acc.y = 0.f; acc.z = 0.f; acc.w = 0.f;
  };

  if (P0 < P4) {
    int cb = P0;
    int2 mse = csr[(size_t)(cb + lane)];
    Quad qA = fetchq(0, mse);
    Quad qB;
    int p = P0;
    for (; p + 8 <= P4; p += 8) {
      int p1q = p + 4;
      if (p1q - cb == 64) { cb = p1q; mse = csr[(size_t)(cb + lane)]; }
      qB = fetchq(p1q - cb, mse);
      while (__builtin_expect(p == nb, 0)) {
        flushn(); ++node;
        nb = (node == 1) ? b2v : (node == 2) ? b3v : 0x7FFFFFFF;
      }
      computeq(qA);
      int p2q = p + 8;
      if (p2q - cb == 64) { cb = p2q; mse = csr[(size_t)(cb + lane)]; }
      qA = fetchq(p2q - cb, mse);
      while (__builtin_expect(p + 4 == nb, 0)) {
        flushn(); ++node;
        nb = (node == 1) ? b2v : (node == 2) ? b3v : 0x7FFFFFFF;
      }
      computeq(qB);
    }
    if (p < P4) {
      while (__builtin_expect(p == nb, 0)) {
        flushn(); ++node;
        nb = (node == 1) ? b2v : (node == 2) ? b3v : 0x7FFFFFFF;
      }
      computeq(qA);
    }
  }
  while (node < 4) { flushn(); ++node; }
  __syncthreads();

  // ---- phase 2: [16,256] @ [256,256] ----
  int colb = lane & 15, rowf = lane & 15, kgrp = (lane >> 4) * 8;
  int c0 = wv * 64;
  const short* wtc = WT + (size_t)(c0 + colb) * 256;
  const u16* Ar = &As[rowf][0];
  f32x4 acc0 = {0.f, 0.f, 0.f, 0.f}, acc1 = acc0, acc2 = acc0, acc3 = acc0;
  short8 b0 = *(const short8*)(wtc + kgrp);
  short8 b1 = *(const short8*)(wtc + 4096 + kgrp);
  short8 b2 = *(const short8*)(wtc + 8192 + kgrp);
  short8 b3 = *(const short8*)(wtc + 12288 + kgrp);
#pragma unroll
  for (int kt = 0; kt < 8; ++kt) {
    int k0 = kt * 32 + kgrp;
    short8 af = *(const short8*)(Ar + k0);
    short8 n0, n1, n2, n3;
    if (kt < 7) {
      int kn = k0 + 32;
      n0 = *(const short8*)(wtc + kn);
      n1 = *(const short8*)(wtc + 4096 + kn);
      n2 = *(const short8*)(wtc + 8192 + kn);
      n3 = *(const short8*)(wtc + 12288 + kn);
    }
    acc0 = __builtin_amdgcn_mfma_f32_16x16x32_bf16(af, b0, acc0, 0, 0, 0);
    acc1 = __builtin_amdgcn_mfma_f32_16x16x32_bf16(af, b1, acc1, 0, 0, 0);
    acc2 = __builtin_amdgcn_mfma_f32_16x16x32_bf16(af, b2, acc2, 0, 0, 0);
    acc3 = __builtin_amdgcn_mfma_f32_16x16x32_bf16(af, b3, acc3, 0, 0, 0);
    if (kt < 7) { b0 = n0; b1 = n1; b2 = n2; b3 = n3; }
  }
  int rbase = (lane >> 4) * 4;
#pragma unroll
  for (int nbk = 0; nbk < 4; ++nbk) {
    f32x4 a = (nbk == 0) ? acc0 : (nbk == 1) ? acc1 : (nbk == 2) ? acc2 : acc3;
    int col = c0 + nbk * 16 + colb;
    float bv = bias[col];
#pragma unroll
    for (int rr = 0; rr < 4; ++rr) {
      int vv = nbase + rbase + rr;
      if (vv < N) {
        float val = a[rr] + bv;
        if (houtf) houtf[(size_t)vv * 256 + col] = val;
        if (houtbf) houtbf[(size_t)vv * 256 + col] = (u16)f2bf(val);
      }
    }
  }
}

// out = h @ out_w[256,3] + out_b ; one node per wave
__global__ void head_kernel(const float* __restrict__ h, const float* __restrict__ ow,
                            const float* __restrict__ ob, float* __restrict__ out, int n) {
  __shared__ float sw[768];
  for (int i = threadIdx.x; i < 768; i += 256) sw[i] = ow[i];
  __syncthreads();
  int wv = threadIdx.x >> 6, lane = threadIdx.x & 63;
  int v = blockIdx.x * 4 + wv;
  if (v >= n) return;
  f32x4 hv = *(const f32x4*)(h + (size_t)v * 256 + lane * 4);
  int d0 = lane * 4;
#pragma unroll
  for (int o = 0; o < 3; ++o) {
    float s = hv.x * sw[(d0 + 0) * 3 + o] + hv.y * sw[(d0 + 1) * 3 + o] +
              hv.z * sw[(d0 + 2) * 3 + o] + hv.w * sw[(d0 + 3) * 3 + o];
#pragma unroll
    for (int off = 32; off > 0; off >>= 1) s += __shfl_down(s, off);
    if (lane == 0) out[(size_t)v * 3 + o] = s + ob[o];
  }
}

// ---------------------------------------------------------------------------
extern "C" void kernel_launch(void* const* d_in, const int* in_sizes, int n_in,
                              void* d_out, int out_size, void* d_ws, size_t ws_size,
                              hipStream_t stream) {
  const float* x     = (const float*)d_in[0];
  const float* eattr = (const float*)d_in[1];
  const int*   eidx  = (const int*)d_in[2];
  const float* nw1 = (const float*)d_in[3];
  const float* nb1 = (const float*)d_in[4];
  const float* nw2 = (const float*)d_in[5];
  const float* nb2 = (const float*)d_in[6];
  const float* ew1 = (const float*)d_in[7];
  const float* eb1 = (const float*)d_in[8];
  const float* ew2 = (const float*)d_in[9];
  const float* eb2 = (const float*)d_in[10];
  const float* gw  = (const float*)d_in[11];
  const float* gb  = (const float*)d_in[12];
  const float* ow  = (const float*)d_in[13];
  const float* ob  = (const float*)d_in[14];

  int N = in_sizes[0];
  int E = in_sizes[1];
  const int* srcA = eidx;
  const int* dstA = eidx + E;
  int EP = E + 3 * N + 768;  // padded csr slots + chunk slack

  char* ws = (char*)d_ws;
  auto al = [](size_t v) { return (v + 255) & ~(size_t)255; };
  size_t off = 0;
  float* hA    = (float*)(ws + off); off = al(off + (size_t)N * 256 * 4);   // final f32 h
  u16* hbfA    = (u16*)(ws + off);   off = al(off + (size_t)N * 256 * 2);
  u16* hbfB    = (u16*)(ws + off);   off = al(off + (size_t)N * 256 * 2);
  short* WT    = (short*)(ws + off); off = al(off + (size_t)4 * 256 * 256 * 2);
  float* knN   = (float*)(ws + off); off = al(off + 128 * 4);
  float* AN    = (float*)(ws + off); off = al(off + 129 * 256 * 4);
  float* BN    = (float*)(ws + off); off = al(off + 129 * 256 * 4);
  float* knE   = (float*)(ws + off); off = al(off + 128 * 4);
  float* AE    = (float*)(ws + off); off = al(off + 129 * 256 * 4);
  float* BE    = (float*)(ws + off); off = al(off + 129 * 256 * 4);
  unsigned* ABE = (unsigned*)(ws + off); off = al(off + 129 * 256 * 4);
  int* rankN   = (int*)(ws + off);   off = al(off + 128 * 4);
  int* act0N   = (int*)(ws + off);   off = al(off + 128 * 4);
  int* rankE   = (int*)(ws + off);   off = al(off + 128 * 4);
  int* act0E   = (int*)(ws + off);   off = al(off + 128 * 4);
  int* segselE = (int*)(ws + off);   off = al(off + 2 * 4);
  int* rowSt   = (int*)(ws + off);   off = al(off + (size_t)(N + 1) * 4);
  int* counts  = (int*)(ws + off);   off = al(off + (size_t)N * 4);
  int* bsums   = (int*)(ws + off);   off = al(off + 256 * 4);
  int2* csr    = (int2*)(ws + off);  off = al(off + (size_t)EP * 8);
  (void)ws_size; (void)n_in; (void)out_size;

  // encoder tables (parallel build)
  build_meta_kernel<<<1, 128, 0, stream>>>(nw1, nb1, knN, rankN, act0N, nullptr);
  build_meta_kernel<<<1, 128, 0, stream>>>(ew1, eb1, knE, rankE, act0E, segselE);
  build_seg_kernel<<<129, 256, 0, stream>>>(nw1, nb1, nw2, nb2, rankN, act0N, AN, BN, nullptr);
  build_seg_kernel<<<129, 256, 0, stream>>>(ew1, eb1, ew2, eb2, rankE, act0E, AE, BE, ABE);

  // node encoder -> hbfA
  apply_enc_kernel<<<(N + 15) / 16, 256, 0, stream>>>(x, N, knN, AN, BN, hbfA);

  // CSR build (padded, quad-aligned rows)
  int gN = (N + 255) / 256, gE = (E + 255) / 256, gEP = (EP + 255) / 256;
  zero_kernel<<<gN, 256, 0, stream>>>(counts, N);
  hist_kernel<<<gE, 256, 0, stream>>>(dstA, E, counts);
  scan_p1_kernel<<<gN, 256, 0, stream>>>(counts, N, bsums);
  scan_p2_kernel<<<1, 256, 0, stream>>>(bsums, gN, rowSt, N);
  scan_p3_kernel<<<gN, 256, 0, stream>>>(counts, N, bsums, rowSt);
  initcsr_kernel<<<gEP, 256, 0, stream>>>(csr, EP);
  zero_kernel<<<gN, 256, 0, stream>>>(counts, N);
  fill_kernel<<<gE, 256, 0, stream>>>(srcA, dstA, eattr, E, rowSt, counts, knE, csr);
  // NOTE: after fill, counts[v] == real degree (cursor final value)

  // weights -> bf16 transposed
  convw_kernel<<<4 * 256, 256, 0, stream>>>(gw, WT);

  // fused layers
  u16* hbc = hbfA;
  u16* hbn = hbfB;
  int gLayer = (N + 15) / 16;
  for (int l = 0; l < 4; ++l) {
    float* hf = (l == 3) ? hA : nullptr;      // f32 only needed by head
    u16* hbo = (l == 3) ? nullptr : hbn;
    layer_kernel<<<gLayer, 256, 0, stream>>>(hbc, csr, rowSt, counts, ABE, segselE,
                                             WT + (size_t)l * 256 * 256,
                                             gb + (size_t)l * 256, hf, hbo, N);
    u16* t = hbc; hbc = hbn; hbn = t;
  }

  head_kernel<<<(N + 3) / 4, 256, 0, stream>>>(hA, ow, ob, (float*)d_out, N);
}